// Round 2
// baseline (1402.360 us; speedup 1.0000x reference)
//
#include <hip/hip_runtime.h>

#define NBASIN 2000
#define NTIME  730
#define NMULT  8
#define NPAR   12
#define LENF   15

// ---------------------------------------------------------------------------
// Kernel 1: the time scan. One thread per (basin, mul) trajectory.
// 250 blocks x 64 threads = 16000 threads. lane g = b*8 + m, so P/T/PET loads
// (layout [t][b][m]) are fully coalesced per wave. PF-deep register prefetch
// pipeline keeps ~65 loads in flight to hide HBM latency at 1 wave/CU.
// Writes Q (mean over m) to out[b*NT + t].
// ---------------------------------------------------------------------------
__global__ __launch_bounds__(64, 1)
void prms_scan_kernel(const float* __restrict__ P, const float* __restrict__ T,
                      const float* __restrict__ PET, const float* __restrict__ params,
                      float* __restrict__ Q) {
  constexpr int PF = 5;                       // 5 divides 730 exactly
  const int g = blockIdx.x * 64 + threadIdx.x;   // 0 .. 15999
  const int b = g >> 3;
  const int m = g & 7;

  const float* __restrict__ Pg = P + g;
  const float* __restrict__ Tg = T + g;
  const float* __restrict__ Eg = PET + g;
  const float* __restrict__ pbase = params + (size_t)b * (NTIME * NPAR * NMULT) + m;

  float fp[PF], ft[PF], fe[PF], fpr[PF][10];

#define LOADSTEP(j, t) do {                                                  \
    const size_t off_ = (size_t)(t) * (NBASIN * NMULT);                      \
    fp[j] = Pg[off_]; ft[j] = Tg[off_]; fe[j] = Eg[off_];                    \
    const float* pb_ = pbase + (size_t)(t) * (NPAR * NMULT);                 \
    _Pragma("unroll")                                                        \
    for (int p_ = 0; p_ < 10; ++p_) fpr[j][p_] = pb_[p_ * NMULT];            \
  } while (0)

#pragma unroll
  for (int j = 0; j < PF; ++j) LOADSTEP(j, j);

  float Ssnow = 0.0f, Ssoil = 0.0f, Sgw = 0.0f;

  for (int tb = 0; tb < NTIME; tb += PF) {
#pragma unroll
    for (int j = 0; j < PF; ++j) {
      const int t = tb + j;

      // consume current buffer (copy to locals), then refill it for t+PF
      const float pv = fp[j], tv = ft[j], pe = fe[j];
      float pr[10];
#pragma unroll
      for (int p = 0; p < 10; ++p) pr[p] = fpr[j][p];
      if (t + PF < NTIME) LOADSTEP(j, t + PF);

      // parameter descaling: lb + (ub-lb)*x
      const float tt    = -3.0f + 8.0f    * pr[0];
      const float ddf   =         20.0f   * pr[1];
      const float smax  =  1.0f + 1999.0f * pr[2];
      const float scn   = pr[3];
      const float scx   = pr[4];
      const float pexp  =         10.0f   * pr[5];
      const float krech =         20.0f   * pr[6];
      const float kif1  = pr[7];
      const float kif2  =         0.01f   * pr[8];
      const float kbf   = pr[9];

      // bucket-model step (op order matches the JAX reference; dt == 1)
      const float fsnow    = (tv <= tt) ? 1.0f : 0.0f;
      const float snowfall = pv * fsnow;
      const float rain     = pv * (1.0f - fsnow);
      const float melt     = fmaxf(fminf(ddf * (tv - tt), Ssnow), 0.0f);
      Ssnow = Ssnow + snowfall - melt;
      const float infil = rain + melt;
      const float qsat  = (scn + (scx - scn) * Ssoil / smax) * infil;
      const float evap  = fminf(Ssoil / smax * pe, Ssoil);
      const float rech  = krech * powf(fmaxf(Ssoil, 0.0f) / smax + 1e-6f, pexp);
      Ssoil = fmaxf(Ssoil + infil - qsat - evap - rech, 0.0f);
      const float Sc  = fmaxf(Sgw, 0.0f);
      const float qif = fminf(Sc, kif1 * Sc + kif2 * (Sc * Sc));
      const float qbf = kbf * Sc;
      Sgw = fmaxf(Sgw + rech - qif - qbf, 0.0f);

      float q = qsat + qif + qbf;
      // mean over the 8 mul-lanes of this basin (lanes are contiguous groups of 8)
      q += __shfl_xor(q, 1, 8);
      q += __shfl_xor(q, 2, 8);
      q += __shfl_xor(q, 4, 8);
      if (m == 0) Q[(size_t)b * NTIME + t] = q * 0.125f;
    }
  }
#undef LOADSTEP
}

// ---------------------------------------------------------------------------
// Kernel 2: gamma unit-hydrograph weights + causal 15-tap conv, in place on
// d_out. One block per basin; Q row staged to LDS first, so in-place is safe.
// routa/routb come from params[b, NT-1, param 10/11] (known without the scan).
// ---------------------------------------------------------------------------
__global__ __launch_bounds__(256)
void prms_uhconv_kernel(const float* __restrict__ params, float* __restrict__ QO) {
  const int b = blockIdx.x;
  __shared__ float w[LENF];
  __shared__ float qrow[NTIME];

  if (threadIdx.x == 0) {
    const float* pr = params + (size_t)b * (NTIME * NPAR * NMULT)
                             + (size_t)(NTIME - 1) * (NPAR * NMULT) + 10 * NMULT;
    float ra = 0.0f, rb = 0.0f;
    for (int mm = 0; mm < NMULT; ++mm) {
      ra += 3.0f * pr[mm];           // lb=0, ub=3
      rb += 5.0f * pr[NMULT + mm];   // lb=0, ub=5
    }
    ra *= 0.125f;
    rb *= 0.125f;
    const float aa = fmaxf(ra, 0.0f) + 0.1f;
    const float th = fmaxf(rb, 0.0f) + 0.5f;
    const float denom = expf(lgammaf(aa)) * powf(th, aa);
    float s = 0.0f;
    float tmp[LENF];
    for (int k = 0; k < LENF; ++k) {
      const float tk = (float)k + 0.5f;
      tmp[k] = powf(tk, aa - 1.0f) * expf(-tk / th) / denom;
      s += tmp[k];
    }
    for (int k = 0; k < LENF; ++k) w[k] = tmp[k] / s;
  }

  for (int i = threadIdx.x; i < NTIME; i += blockDim.x)
    qrow[i] = QO[(size_t)b * NTIME + i];
  __syncthreads();

  for (int t = threadIdx.x; t < NTIME; t += blockDim.x) {
    float acc = 0.0f;
#pragma unroll
    for (int k = 0; k < LENF; ++k) {
      if (k <= t) acc += w[k] * qrow[t - k];
    }
    QO[(size_t)b * NTIME + t] = acc;
  }
}

// ---------------------------------------------------------------------------
extern "C" void kernel_launch(void* const* d_in, const int* in_sizes, int n_in,
                              void* d_out, int out_size, void* d_ws, size_t ws_size,
                              hipStream_t stream) {
  const float* P      = (const float*)d_in[0];
  const float* T      = (const float*)d_in[1];
  const float* PET    = (const float*)d_in[2];
  const float* params = (const float*)d_in[3];
  float* out = (float*)d_out;

  // scan: 16000 trajectories, 64 threads/block -> 250 blocks (~1 wave/CU)
  prms_scan_kernel<<<(NBASIN * NMULT) / 64, 64, 0, stream>>>(P, T, PET, params, out);
  // per-basin gamma UH + causal conv, in place on out
  prms_uhconv_kernel<<<NBASIN, 256, 0, stream>>>(params, out);
}